// Round 1
// baseline (44.881 us; speedup 1.0000x reference)
//
#include <hip/hip_runtime.h>
#include <math.h>

#define D 20
#define BATCH_ROWS 1000000
#define BLOCK 256
#define NB ((BATCH_ROWS + BLOCK - 1) / BLOCK)   // 3907 blocks

// ws layout (all regions written before read on every launch -> poison-safe):
//   [0, NB*2*8)          : per-block partial sums (S, Sabs) as doubles = 62512 B
//   [62720, 62720+1600)  : A = W^T @ R   (20x20 floats)
//   [64320, 64320+80)    : c = b @ R + 1 (20 floats)
#define A_OFF 62720
#define C_OFF (A_OFF + D*D*4)

// ---------------------------------------------------------------------------
// Setup: fold the first two linear layers.
//   A[j][m] = sum_i W[i][j] * R[i][m]
//   c[m]    = 1 + sum_i b[i] * R[i][m]
// ---------------------------------------------------------------------------
__global__ __launch_bounds__(512) void setup_kernel(
    const float* __restrict__ W, const float* __restrict__ b,
    const float* __restrict__ R, float* __restrict__ A, float* __restrict__ c) {
  int t = threadIdx.x;
  if (t < D * D) {
    int j = t / D, m = t % D;
    float s = 0.f;
#pragma unroll
    for (int i = 0; i < D; ++i) s = fmaf(W[i * D + j], R[i * D + m], s);
    A[j * D + m] = s;
  } else if (t < D * D + D) {
    int m = t - D * D;
    float s = 1.0f;
#pragma unroll
    for (int i = 0; i < D; ++i) s = fmaf(b[i], R[i * D + m], s);
    c[m] = s;
  }
}

// ---------------------------------------------------------------------------
// Main: one thread per row.
//   X2 = relu(x @ A + c);  X3 = X2 @ W^T + b;  accumulate (sum, abs-sum).
// A/W/b/c have wave-uniform addresses -> scalar loads (SGPR operands to FMA).
// ---------------------------------------------------------------------------
__global__ __launch_bounds__(BLOCK) void main_kernel(
    const float* __restrict__ X, const float* __restrict__ W,
    const float* __restrict__ b, const float* __restrict__ A,
    const float* __restrict__ c, double* __restrict__ partial) {
  int row = blockIdx.x * BLOCK + threadIdx.x;
  float s = 0.f, sa = 0.f;
  if (row < BATCH_ROWS) {
    const float4* xr = (const float4*)(X + (size_t)row * D);  // 80B row, 16B aligned
    float4 v0 = xr[0], v1 = xr[1], v2 = xr[2], v3 = xr[3], v4 = xr[4];
    float x[D] = {v0.x, v0.y, v0.z, v0.w, v1.x, v1.y, v1.z, v1.w,
                  v2.x, v2.y, v2.z, v2.w, v3.x, v3.y, v3.z, v3.w,
                  v4.x, v4.y, v4.z, v4.w};
    float acc[D];
#pragma unroll
    for (int m = 0; m < D; ++m) acc[m] = c[m];
#pragma unroll
    for (int j = 0; j < D; ++j) {
#pragma unroll
      for (int m = 0; m < D; ++m) acc[m] = fmaf(x[j], A[j * D + m], acc[m]);
    }
#pragma unroll
    for (int m = 0; m < D; ++m) acc[m] = fmaxf(acc[m], 0.f);  // relu -> X2
    float o[D];
#pragma unroll
    for (int n = 0; n < D; ++n) o[n] = b[n];
#pragma unroll
    for (int m = 0; m < D; ++m) {
#pragma unroll
      for (int n = 0; n < D; ++n) o[n] = fmaf(acc[m], W[n * D + m], o[n]);
    }
#pragma unroll
    for (int n = 0; n < D; ++n) { s += o[n]; sa += fabsf(o[n]); }
  }
  // wave64 reduce in double, then 4-wave LDS reduce, one partial write/block
  double ds = (double)s, da = (double)sa;
#pragma unroll
  for (int off = 32; off > 0; off >>= 1) {
    ds += __shfl_down(ds, off, 64);
    da += __shfl_down(da, off, 64);
  }
  __shared__ double red[8];
  int wid = threadIdx.x >> 6;
  if ((threadIdx.x & 63) == 0) { red[wid * 2] = ds; red[wid * 2 + 1] = da; }
  __syncthreads();
  if (threadIdx.x == 0) {
    partial[2 * blockIdx.x]     = red[0] + red[2] + red[4] + red[6];
    partial[2 * blockIdx.x + 1] = red[1] + red[3] + red[5] + red[7];
  }
}

// ---------------------------------------------------------------------------
// Finalize: reduce 3907 partial pairs; halving loop is exact scalar math:
// k = #halvings until abs-sum <= 1; out = ldexp(S, -k).
// ---------------------------------------------------------------------------
__global__ __launch_bounds__(256) void final_kernel(
    const double* __restrict__ partial, float* __restrict__ out) {
  double s = 0.0, sa = 0.0;
  for (int i = threadIdx.x; i < NB; i += 256) {
    s += partial[2 * i];
    sa += partial[2 * i + 1];
  }
#pragma unroll
  for (int off = 32; off > 0; off >>= 1) {
    s += __shfl_down(s, off, 64);
    sa += __shfl_down(sa, off, 64);
  }
  __shared__ double red[8];
  int wid = threadIdx.x >> 6;
  if ((threadIdx.x & 63) == 0) { red[wid * 2] = s; red[wid * 2 + 1] = sa; }
  __syncthreads();
  if (threadIdx.x == 0) {
    double S  = red[0] + red[2] + red[4] + red[6];
    double SA = red[1] + red[3] + red[5] + red[7];
    int k = 0;
    double t = SA;
    while (t > 1.0 && k < 4096) { t *= 0.5; ++k; }  // exact: /2 per reference iter
    out[0] = (float)ldexp(S, -k);
  }
}

extern "C" void kernel_launch(void* const* d_in, const int* in_sizes, int n_in,
                              void* d_out, int out_size, void* d_ws, size_t ws_size,
                              hipStream_t stream) {
  const float* X = (const float*)d_in[0];
  const float* W = (const float*)d_in[1];
  const float* b = (const float*)d_in[2];
  const float* R = (const float*)d_in[3];
  char* ws = (char*)d_ws;
  double* partial = (double*)ws;
  float* A = (float*)(ws + A_OFF);
  float* c = (float*)(ws + C_OFF);

  setup_kernel<<<1, 512, 0, stream>>>(W, b, R, A, c);
  main_kernel<<<NB, BLOCK, 0, stream>>>(X, W, b, A, c, partial);
  final_kernel<<<1, 256, 0, stream>>>(partial, (float*)d_out);
}